// Round 3
// baseline (343.114 us; speedup 1.0000x reference)
//
#include <hip/hip_runtime.h>
#include <stdint.h>

#define XDIM 131
#define LATENT 128
#define FDIM 32
#define GSZ 513
#define SDF_IN 227
#define FEAT0 136            // feats live in cols 136..231 (8-aligned); W0 rows permuted to match
#define BSTRIDE 2064         // bytes per c-block: 128 rows * 16B + 16B pad (breaks bank aliasing)

typedef __attribute__((ext_vector_type(8))) short bf16x8;
typedef __attribute__((ext_vector_type(4))) float f32x4;
typedef unsigned int uint32;

__device__ __forceinline__ unsigned short f2bf(float f) {
  uint32 u = __float_as_uint(f);
  u += 0x7fffu + ((u >> 16) & 1u);   // RTNE
  return (unsigned short)(u >> 16);
}
__device__ __forceinline__ float bf2f(unsigned short s) {
  return __uint_as_float(((uint32)s) << 16);
}
// pack two floats -> one dword of 2 bf16, pure register ops (no union/alloca!)
__device__ __forceinline__ uint32 pk2bf(float a, float b) {
  return (uint32)f2bf(a) | ((uint32)f2bf(b) << 16);
}

// LDS layout: element (r, c) -> c-block blk_of(c), 16B unit slot16(r), halfword (c&7).
__device__ __forceinline__ int slot16(int r) { return (r * 16) ^ (((r >> 3) & 1) << 5); }
__device__ __forceinline__ int blk_of(int c) { return (c >> 5) * 4 + ((c >> 3) & 3); }
__device__ __forceinline__ int act_byte(int r, int c) {
  return blk_of(c) * BSTRIDE + slot16(r) + (c & 7) * 2;
}

// ---------------- prep: P [3][32][513][513] f32 -> Pt [3][513][513][32] bf16
__global__ void prep_pt(const float* __restrict__ P, unsigned short* __restrict__ Pt) {
  int i = blockIdx.x * 256 + threadIdx.x;
  const int CELLS = 3 * GSZ * GSZ;
  if (i >= CELLS) return;
  int pl = i / (GSZ * GSZ);
  int yx = i - pl * (GSZ * GSZ);
  const float* src = P + (size_t)pl * FDIM * GSZ * GSZ + yx;
  const size_t GG = (size_t)GSZ * GSZ;
  uint4* dst = (uint4*)(Pt + (size_t)i * 32);
#pragma unroll
  for (int w = 0; w < 4; ++w) {
    uint4 t;
    t.x = pk2bf(src[(w * 8 + 0) * GG], src[(w * 8 + 1) * GG]);
    t.y = pk2bf(src[(w * 8 + 2) * GG], src[(w * 8 + 3) * GG]);
    t.z = pk2bf(src[(w * 8 + 4) * GG], src[(w * 8 + 5) * GG]);
    t.w = pk2bf(src[(w * 8 + 6) * GG], src[(w * 8 + 7) * GG]);
    dst[w] = t;
  }
}

// ---------------- prep: W0/W1 -> bf16 MFMA B-frag order [kb][g][n][8], W0 K-permuted
__global__ void prep_w(const float* __restrict__ W0, const float* __restrict__ W1,
                       unsigned short* __restrict__ W0g, unsigned short* __restrict__ W1g) {
  int i = blockIdx.x * 256 + threadIdx.x;  // 0..16383
  int sel = i >> 13;
  int t = i & 8191;
  int kb = t >> 10;
  int g  = (t >> 8) & 3;
  int n  = t & 255;
  float vv[8];
#pragma unroll
  for (int j = 0; j < 8; ++j) {
    int k = kb * 32 + g * 8 + j;           // our column index k'
    float val;
    if (sel == 0) {
      int src = (k < 131) ? k : ((k >= FEAT0 && k < FEAT0 + 96) ? k - 5 : -1);
      val = (src >= 0) ? W0[src * 256 + n] : 0.f;
    } else {
      val = W1[k * 256 + n];
    }
    vv[j] = val;
  }
  uint4 o;
  o.x = pk2bf(vv[0], vv[1]);
  o.y = pk2bf(vv[2], vv[3]);
  o.z = pk2bf(vv[4], vv[5]);
  o.w = pk2bf(vv[6], vv[7]);
  unsigned short* dst = (sel == 0 ? W0g : W1g) + (size_t)t * 8;
  *(uint4*)dst = o;
}

__device__ __forceinline__ void gemm_layer(unsigned char* actb,
                                           const unsigned short* __restrict__ Wg,
                                           const float* __restrict__ bias,
                                           int rg, int cg, int lr, int lg)
{
  f32x4 acc[4][4];
#pragma unroll
  for (int mf = 0; mf < 4; ++mf)
#pragma unroll
    for (int nf = 0; nf < 4; ++nf) acc[mf][nf] = (f32x4){0.f, 0.f, 0.f, 0.f};

  float bs[4];
#pragma unroll
  for (int nf = 0; nf < 4; ++nf) bs[nf] = bias[cg * 64 + nf * 16 + lr];

#pragma unroll
  for (int kb = 0; kb < 8; ++kb) {
    bf16x8 a[4], b[4];
    const int ab = (kb * 4 + lg) * BSTRIDE;
#pragma unroll
    for (int mf = 0; mf < 4; ++mf)
      a[mf] = *(const bf16x8*)(actb + ab + slot16(rg * 64 + mf * 16 + lr));
#pragma unroll
    for (int nf = 0; nf < 4; ++nf)
      b[nf] = *(const bf16x8*)(Wg + (size_t)(kb * 4 + lg) * 2048 + (size_t)(cg * 64 + nf * 16 + lr) * 8);
#pragma unroll
    for (int mf = 0; mf < 4; ++mf)
#pragma unroll
      for (int nf = 0; nf < 4; ++nf)
        acc[mf][nf] = __builtin_amdgcn_mfma_f32_16x16x32_bf16(a[mf], b[nf], acc[mf][nf], 0, 0, 0);
  }
  __syncthreads();   // all reads of act done before overwrite with h
#pragma unroll
  for (int mf = 0; mf < 4; ++mf)
#pragma unroll
    for (int nf = 0; nf < 4; ++nf) {
      int c = cg * 64 + nf * 16 + lr;
      unsigned char* dst = actb + blk_of(c) * BSTRIDE + (c & 7) * 2;
#pragma unroll
      for (int reg = 0; reg < 4; ++reg) {
        int r = rg * 64 + mf * 16 + lg * 4 + reg;
        float vv = fmaxf(acc[mf][nf][reg] + bs[nf], 0.f);
        *(unsigned short*)(dst + slot16(r)) = f2bf(vv);
      }
    }
  __syncthreads();
}

template<int USE_PT>
__global__ __launch_bounds__(512, 4) void sdf_main(
    const float* __restrict__ x, const float* __restrict__ P,
    const unsigned short* __restrict__ Pt,
    const unsigned short* __restrict__ W0g, const unsigned short* __restrict__ W1g,
    const float* __restrict__ b0, const float* __restrict__ b1,
    const float* __restrict__ W2, const float* __restrict__ b2v,
    float* __restrict__ out, int Npts)
{
  __shared__ __align__(16) unsigned char actb[32 * BSTRIDE];   // 66048 B

  const int tid = threadIdx.x;
  const int p0 = blockIdx.x * 128;

  // zero pad regions: block 16 (cols 128..135) and blocks 29..31 (cols 232..255).
  // 129 + 387 = 516 uint4 items; grid-stride so ALL are covered (512 threads).
  for (int z = tid; z < 516; z += 512) {
    uint4 zz = {0u, 0u, 0u, 0u};
    if (z < 129) ((uint4*)(actb + 16 * BSTRIDE))[z] = zz;
    else         ((uint4*)(actb + 29 * BSTRIDE))[z - 129] = zz;
  }
  __syncthreads();

  // ---- part A: x cols 0..127 -> cols 0..127, vectorized (8 cols per task)
#pragma unroll
  for (int i = 0; i < 4; ++i) {
    int t = i * 512 + tid;
    int cb = t & 15, r = t >> 4;
    int p = min(p0 + r, Npts - 1);
    const float* src = x + (size_t)p * XDIM + cb * 8;
    uint4 v;
    v.x = pk2bf(src[0], src[1]);
    v.y = pk2bf(src[2], src[3]);
    v.z = pk2bf(src[4], src[5]);
    v.w = pk2bf(src[6], src[7]);
    *(uint4*)(actb + cb * BSTRIDE + slot16(r)) = v;
  }
  // coords cols 128..130 (cols 131..135 stay zero; W0 rows there are zero anyway)
  if (tid < 128) {
    int r = tid;
    int p = min(p0 + r, Npts - 1);
#pragma unroll
    for (int j = 0; j < 3; ++j)
      *(unsigned short*)(actb + act_byte(r, 128 + j)) = f2bf(x[(size_t)p * XDIM + 128 + j]);
  }

  // ---- part B: triplane bilinear feats -> cols 136..231 (8-aligned, b128 writes)
  {
    int p_l = tid >> 2;
    int q = tid & 3;
    int p = min(p0 + p_l, Npts - 1);
    const float* xr = x + (size_t)p * XDIM + LATENT;
    float cc0 = xr[0], cc1 = xr[1], cc2 = xr[2];
#pragma unroll
    for (int pl = 0; pl < 3; ++pl) {
      float u = (pl == 2) ? cc1 : cc0;
      float v = (pl == 0) ? cc1 : cc2;
      float gx = fminf(fmaxf((u + 1.f) * 256.f, 0.f), 512.f);
      float gy = fminf(fmaxf((v + 1.f) * 256.f, 0.f), 512.f);
      float x0f = floorf(gx), y0f = floorf(gy);
      int x0 = (int)x0f, y0 = (int)y0f;
      int x1 = min(x0 + 1, GSZ - 1), y1 = min(y0 + 1, GSZ - 1);
      float wx = gx - x0f, wy = gy - y0f;
      float w00 = (1.f - wx) * (1.f - wy), w01 = wx * (1.f - wy);
      float w10 = (1.f - wx) * wy,        w11 = wx * wy;
      float f[8];
      if (USE_PT) {
        bf16x8 v00 = *(const bf16x8*)(Pt + ((size_t)((pl * GSZ + y0) * GSZ + x0)) * 32 + q * 8);
        bf16x8 v01 = *(const bf16x8*)(Pt + ((size_t)((pl * GSZ + y0) * GSZ + x1)) * 32 + q * 8);
        bf16x8 v10 = *(const bf16x8*)(Pt + ((size_t)((pl * GSZ + y1) * GSZ + x0)) * 32 + q * 8);
        bf16x8 v11 = *(const bf16x8*)(Pt + ((size_t)((pl * GSZ + y1) * GSZ + x1)) * 32 + q * 8);
#pragma unroll
        for (int j = 0; j < 8; ++j) {
          f[j] = w00 * bf2f((unsigned short)v00[j])
               + w01 * bf2f((unsigned short)v01[j])
               + w10 * bf2f((unsigned short)v10[j])
               + w11 * bf2f((unsigned short)v11[j]);
        }
      } else {
#pragma unroll
        for (int j = 0; j < 8; ++j) {
          int c = q * 8 + j;
          const float* pc = P + (size_t)(pl * FDIM + c) * GSZ * GSZ;
          f[j] = w00 * pc[y0 * GSZ + x0] + w01 * pc[y0 * GSZ + x1]
               + w10 * pc[y1 * GSZ + x0] + w11 * pc[y1 * GSZ + x1];
        }
      }
      uint4 fv;
      fv.x = pk2bf(f[0], f[1]);
      fv.y = pk2bf(f[2], f[3]);
      fv.z = pk2bf(f[4], f[5]);
      fv.w = pk2bf(f[6], f[7]);
      *(uint4*)(actb + (17 + pl * 4 + q) * BSTRIDE + slot16(p_l)) = fv;
    }
  }
  __syncthreads();

  const int lane = tid & 63, wid = tid >> 6;
  const int rg = wid >> 2, cg = wid & 3, lr = lane & 15, lg = lane >> 4;

  gemm_layer(actb, W0g, b0, rg, cg, lr, lg);   // layer 0 (K=256, permuted/padded)
  gemm_layer(actb, W1g, b1, rg, cg, lr, lg);   // layer 1 (K=256)

  // ---- layer 2: h @ W2 + b2, vectorized LDS reads, register W2
  {
    int p_l = tid >> 2, q = tid & 3;
    float sum = 0.f;
#pragma unroll
    for (int m = 0; m < 8; ++m) {
      int cbase = m * 32 + q * 8;
      bf16x8 h = *(const bf16x8*)(actb + (m * 4 + q) * BSTRIDE + slot16(p_l));
      float4 wa = *(const float4*)(W2 + cbase);
      float4 wb = *(const float4*)(W2 + cbase + 4);
      sum += bf2f((unsigned short)h[0]) * wa.x + bf2f((unsigned short)h[1]) * wa.y
           + bf2f((unsigned short)h[2]) * wa.z + bf2f((unsigned short)h[3]) * wa.w
           + bf2f((unsigned short)h[4]) * wb.x + bf2f((unsigned short)h[5]) * wb.y
           + bf2f((unsigned short)h[6]) * wb.z + bf2f((unsigned short)h[7]) * wb.w;
    }
    sum += __shfl_xor(sum, 1);
    sum += __shfl_xor(sum, 2);
    if (q == 0) {
      int p = p0 + p_l;
      if (p < Npts) out[p] = sum + b2v[0];
    }
  }
}

extern "C" void kernel_launch(void* const* d_in, const int* in_sizes, int n_in,
                              void* d_out, int out_size, void* d_ws, size_t ws_size,
                              hipStream_t stream)
{
  const float* x  = (const float*)d_in[0];
  const float* P  = (const float*)d_in[1];
  const float* W0 = (const float*)d_in[2];
  const float* b0 = (const float*)d_in[3];
  const float* W1 = (const float*)d_in[4];
  const float* b1 = (const float*)d_in[5];
  const float* W2 = (const float*)d_in[6];
  const float* b2 = (const float*)d_in[7];
  float* out = (float*)d_out;
  int Npts = in_sizes[0] / XDIM;

  const size_t PT_BYTES = (size_t)3 * GSZ * GSZ * 32 * 2;  // ~50.5 MB
  const size_t WG_BYTES = (size_t)8192 * 8 * 2;            // 128 KB each
  char* ws = (char*)d_ws;
  int use_pt = (ws_size >= PT_BYTES + 2 * WG_BYTES) ? 1 : 0;
  unsigned short *Ptb, *W0g, *W1g;
  if (use_pt) {
    Ptb = (unsigned short*)ws;
    W0g = (unsigned short*)(ws + PT_BYTES);
    W1g = (unsigned short*)(ws + PT_BYTES + WG_BYTES);
  } else {
    Ptb = nullptr;
    W0g = (unsigned short*)ws;
    W1g = (unsigned short*)(ws + WG_BYTES);
  }

  prep_w<<<64, 256, 0, stream>>>(W0, W1, W0g, W1g);
  if (use_pt) prep_pt<<<(3 * GSZ * GSZ + 255) / 256, 256, 0, stream>>>(P, Ptb);

  int nblk = (Npts + 127) / 128;
  if (use_pt)
    sdf_main<1><<<nblk, 512, 0, stream>>>(x, P, Ptb, W0g, W1g, b0, b1, W2, b2, out, Npts);
  else
    sdf_main<0><<<nblk, 512, 0, stream>>>(x, P, Ptb, W0g, W1g, b0, b1, W2, b2, out, Npts);
}

// Round 4
// 303.534 us; speedup vs baseline: 1.1304x; 1.1304x over previous
//
#include <hip/hip_runtime.h>
#include <stdint.h>

#define XDIM 131
#define LATENT 128
#define FDIM 32
#define GSZ 513
#define SDF_IN 227
#define FEAT0 136            // feats live in cols 136..231 (8-aligned); W0 rows permuted to match
#define BSTRIDE 2064         // bytes per c-block: 128 rows * 16B + 16B pad (breaks bank aliasing)

typedef __attribute__((ext_vector_type(8))) short bf16x8;
typedef __attribute__((ext_vector_type(4))) float f32x4;
typedef unsigned int uint32;

__device__ __forceinline__ unsigned short f2bf(float f) {
  uint32 u = __float_as_uint(f);
  u += 0x7fffu + ((u >> 16) & 1u);   // RTNE
  return (unsigned short)(u >> 16);
}
__device__ __forceinline__ float bf2f(unsigned short s) {
  return __uint_as_float(((uint32)s) << 16);
}
// pack two floats -> one dword of 2 bf16, pure register ops
__device__ __forceinline__ uint32 pk2bf(float a, float b) {
  return (uint32)f2bf(a) | ((uint32)f2bf(b) << 16);
}

// LDS layout: element (r, c) -> c-block blk_of(c), 16B unit slot16(r), halfword (c&7).
__device__ __forceinline__ int slot16(int r) { return (r * 16) ^ (((r >> 3) & 1) << 5); }
__device__ __forceinline__ int blk_of(int c) { return (c >> 5) * 4 + ((c >> 3) & 3); }
__device__ __forceinline__ int act_byte(int r, int c) {
  return blk_of(c) * BSTRIDE + slot16(r) + (c & 7) * 2;
}

// ---------------- prep: P [3][32][513][513] f32 -> Pt [3][513][513][32] bf16
__global__ void prep_pt(const float* __restrict__ P, unsigned short* __restrict__ Pt) {
  int i = blockIdx.x * 256 + threadIdx.x;
  const int CELLS = 3 * GSZ * GSZ;
  if (i >= CELLS) return;
  int pl = i / (GSZ * GSZ);
  int yx = i - pl * (GSZ * GSZ);
  const float* src = P + (size_t)pl * FDIM * GSZ * GSZ + yx;
  const size_t GG = (size_t)GSZ * GSZ;
  uint4* dst = (uint4*)(Pt + (size_t)i * 32);
#pragma unroll
  for (int w = 0; w < 4; ++w) {
    uint4 t;
    t.x = pk2bf(src[(w * 8 + 0) * GG], src[(w * 8 + 1) * GG]);
    t.y = pk2bf(src[(w * 8 + 2) * GG], src[(w * 8 + 3) * GG]);
    t.z = pk2bf(src[(w * 8 + 4) * GG], src[(w * 8 + 5) * GG]);
    t.w = pk2bf(src[(w * 8 + 6) * GG], src[(w * 8 + 7) * GG]);
    dst[w] = t;
  }
}

// ---------------- prep: W0/W1 -> bf16 MFMA B-frag order [kb][g][n][8], W0 K-permuted
__global__ void prep_w(const float* __restrict__ W0, const float* __restrict__ W1,
                       unsigned short* __restrict__ W0g, unsigned short* __restrict__ W1g) {
  int i = blockIdx.x * 256 + threadIdx.x;  // 0..16383
  int sel = i >> 13;
  int t = i & 8191;
  int kb = t >> 10;
  int g  = (t >> 8) & 3;
  int n  = t & 255;
  float vv[8];
#pragma unroll
  for (int j = 0; j < 8; ++j) {
    int k = kb * 32 + g * 8 + j;           // our column index k'
    float val;
    if (sel == 0) {
      int src = (k < 131) ? k : ((k >= FEAT0 && k < FEAT0 + 96) ? k - 5 : -1);
      val = (src >= 0) ? W0[src * 256 + n] : 0.f;
    } else {
      val = W1[k * 256 + n];
    }
    vv[j] = val;
  }
  uint4 o;
  o.x = pk2bf(vv[0], vv[1]);
  o.y = pk2bf(vv[2], vv[3]);
  o.z = pk2bf(vv[4], vv[5]);
  o.w = pk2bf(vv[6], vv[7]);
  unsigned short* dst = (sel == 0 ? W0g : W1g) + (size_t)t * 8;
  *(uint4*)dst = o;
}

__device__ __forceinline__ void gemm_layer(unsigned char* actb,
                                           const unsigned short* __restrict__ Wg,
                                           const float* __restrict__ bias,
                                           int rg, int cg, int lr, int lg)
{
  f32x4 acc[4][4];
#pragma unroll
  for (int mf = 0; mf < 4; ++mf)
#pragma unroll
    for (int nf = 0; nf < 4; ++nf) acc[mf][nf] = (f32x4){0.f, 0.f, 0.f, 0.f};

  float bs[4];
#pragma unroll
  for (int nf = 0; nf < 4; ++nf) bs[nf] = bias[cg * 64 + nf * 16 + lr];

#pragma unroll
  for (int kb = 0; kb < 8; ++kb) {
    bf16x8 a[4], b[4];
    const int ab = (kb * 4 + lg) * BSTRIDE;
#pragma unroll
    for (int mf = 0; mf < 4; ++mf)
      a[mf] = *(const bf16x8*)(actb + ab + slot16(rg * 64 + mf * 16 + lr));
#pragma unroll
    for (int nf = 0; nf < 4; ++nf)
      b[nf] = *(const bf16x8*)(Wg + (size_t)(kb * 4 + lg) * 2048 + (size_t)(cg * 64 + nf * 16 + lr) * 8);
#pragma unroll
    for (int mf = 0; mf < 4; ++mf)
#pragma unroll
      for (int nf = 0; nf < 4; ++nf)
        acc[mf][nf] = __builtin_amdgcn_mfma_f32_16x16x32_bf16(a[mf], b[nf], acc[mf][nf], 0, 0, 0);
  }
  __syncthreads();   // all reads of act done before overwrite with h
#pragma unroll
  for (int mf = 0; mf < 4; ++mf)
#pragma unroll
    for (int nf = 0; nf < 4; ++nf) {
      int c = cg * 64 + nf * 16 + lr;
      unsigned char* dst = actb + blk_of(c) * BSTRIDE + (c & 7) * 2;
#pragma unroll
      for (int reg = 0; reg < 4; ++reg) {
        int r = rg * 64 + mf * 16 + lg * 4 + reg;
        float vv = fmaxf(acc[mf][nf][reg] + bs[nf], 0.f);
        *(unsigned short*)(dst + slot16(r)) = f2bf(vv);
      }
    }
  __syncthreads();
}

template<int USE_PT>
__global__ __launch_bounds__(512) void sdf_main(
    const float* __restrict__ x, const float* __restrict__ P,
    const unsigned short* __restrict__ Pt,
    const unsigned short* __restrict__ W0g, const unsigned short* __restrict__ W1g,
    const float* __restrict__ b0, const float* __restrict__ b1,
    const float* __restrict__ W2, const float* __restrict__ b2v,
    float* __restrict__ out, int Npts)
{
  __shared__ __align__(16) unsigned char actb[32 * BSTRIDE];   // 66048 B

  const int tid = threadIdx.x;
  const int p0 = blockIdx.x * 128;

  // zero pad regions: block 16 (cols 128..135) and blocks 29..31 (cols 232..255).
  for (int z = tid; z < 516; z += 512) {
    uint4 zz = {0u, 0u, 0u, 0u};
    if (z < 129) ((uint4*)(actb + 16 * BSTRIDE))[z] = zz;
    else         ((uint4*)(actb + 29 * BSTRIDE))[z - 129] = zz;
  }
  __syncthreads();

  // ---- part A: x cols 0..127 -> cols 0..127, vectorized (8 cols per task)
#pragma unroll
  for (int i = 0; i < 4; ++i) {
    int t = i * 512 + tid;
    int cb = t & 15, r = t >> 4;
    int p = min(p0 + r, Npts - 1);
    const float* src = x + (size_t)p * XDIM + cb * 8;
    uint4 v;
    v.x = pk2bf(src[0], src[1]);
    v.y = pk2bf(src[2], src[3]);
    v.z = pk2bf(src[4], src[5]);
    v.w = pk2bf(src[6], src[7]);
    *(uint4*)(actb + cb * BSTRIDE + slot16(r)) = v;
  }
  // coords cols 128..130 (cols 131..135 stay zero; W0 rows there are zero)
  if (tid < 128) {
    int r = tid;
    int p = min(p0 + r, Npts - 1);
#pragma unroll
    for (int j = 0; j < 3; ++j)
      *(unsigned short*)(actb + act_byte(r, 128 + j)) = f2bf(x[(size_t)p * XDIM + 128 + j]);
  }

  // ---- part B: triplane bilinear feats -> cols 136..231, batched gather issue
  {
    int p_l = tid >> 2;
    int q = tid & 3;
    int p = min(p0 + p_l, Npts - 1);
    const float* xr = x + (size_t)p * XDIM + LATENT;
    float cc0 = xr[0], cc1 = xr[1], cc2 = xr[2];

    const unsigned short* ptr00[3]; const unsigned short* ptr01[3];
    const unsigned short* ptr10[3]; const unsigned short* ptr11[3];
    float w00[3], w01[3], w10[3], w11[3];
#pragma unroll
    for (int pl = 0; pl < 3; ++pl) {
      float u = (pl == 2) ? cc1 : cc0;
      float v = (pl == 0) ? cc1 : cc2;
      float gx = fminf(fmaxf((u + 1.f) * 256.f, 0.f), 512.f);
      float gy = fminf(fmaxf((v + 1.f) * 256.f, 0.f), 512.f);
      float x0f = floorf(gx), y0f = floorf(gy);
      int x0 = (int)x0f, y0 = (int)y0f;
      int x1 = min(x0 + 1, GSZ - 1), y1 = min(y0 + 1, GSZ - 1);
      float wx = gx - x0f, wy = gy - y0f;
      w00[pl] = (1.f - wx) * (1.f - wy); w01[pl] = wx * (1.f - wy);
      w10[pl] = (1.f - wx) * wy;         w11[pl] = wx * wy;
      const unsigned short* pb = Pt + (size_t)pl * GSZ * GSZ * 32 + q * 8;
      ptr00[pl] = pb + (size_t)(y0 * GSZ + x0) * 32;
      ptr01[pl] = pb + (size_t)(y0 * GSZ + x1) * 32;
      ptr10[pl] = pb + (size_t)(y1 * GSZ + x0) * 32;
      ptr11[pl] = pb + (size_t)(y1 * GSZ + x1) * 32;
    }
    // issue all 12 loads back-to-back (independent; overlap their latency)
    bf16x8 v00[3], v01[3], v10[3], v11[3];
#pragma unroll
    for (int pl = 0; pl < 3; ++pl) {
      v00[pl] = *(const bf16x8*)ptr00[pl];
      v01[pl] = *(const bf16x8*)ptr01[pl];
      v10[pl] = *(const bf16x8*)ptr10[pl];
      v11[pl] = *(const bf16x8*)ptr11[pl];
    }
#pragma unroll
    for (int pl = 0; pl < 3; ++pl) {
      float f[8];
#pragma unroll
      for (int j = 0; j < 8; ++j) {
        f[j] = w00[pl] * bf2f((unsigned short)v00[pl][j])
             + w01[pl] * bf2f((unsigned short)v01[pl][j])
             + w10[pl] * bf2f((unsigned short)v10[pl][j])
             + w11[pl] * bf2f((unsigned short)v11[pl][j]);
      }
      uint4 fv;
      fv.x = pk2bf(f[0], f[1]);
      fv.y = pk2bf(f[2], f[3]);
      fv.z = pk2bf(f[4], f[5]);
      fv.w = pk2bf(f[6], f[7]);
      *(uint4*)(actb + (17 + pl * 4 + q) * BSTRIDE + slot16(p_l)) = fv;
    }
  }
  __syncthreads();

  const int lane = tid & 63, wid = tid >> 6;
  const int rg = wid >> 2, cg = wid & 3, lr = lane & 15, lg = lane >> 4;

  gemm_layer(actb, W0g, b0, rg, cg, lr, lg);   // layer 0 (K=256, permuted/padded)
  gemm_layer(actb, W1g, b1, rg, cg, lr, lg);   // layer 1 (K=256)

  // ---- layer 2: h @ W2 + b2, vectorized LDS reads, register W2
  {
    int p_l = tid >> 2, q = tid & 3;
    float sum = 0.f;
#pragma unroll
    for (int m = 0; m < 8; ++m) {
      int cbase = m * 32 + q * 8;
      bf16x8 h = *(const bf16x8*)(actb + (m * 4 + q) * BSTRIDE + slot16(p_l));
      float4 wa = *(const float4*)(W2 + cbase);
      float4 wb = *(const float4*)(W2 + cbase + 4);
      sum += bf2f((unsigned short)h[0]) * wa.x + bf2f((unsigned short)h[1]) * wa.y
           + bf2f((unsigned short)h[2]) * wa.z + bf2f((unsigned short)h[3]) * wa.w
           + bf2f((unsigned short)h[4]) * wb.x + bf2f((unsigned short)h[5]) * wb.y
           + bf2f((unsigned short)h[6]) * wb.z + bf2f((unsigned short)h[7]) * wb.w;
    }
    sum += __shfl_xor(sum, 1);
    sum += __shfl_xor(sum, 2);
    if (q == 0) {
      int p = p0 + p_l;
      if (p < Npts) out[p] = sum + b2v[0];
    }
  }
}

extern "C" void kernel_launch(void* const* d_in, const int* in_sizes, int n_in,
                              void* d_out, int out_size, void* d_ws, size_t ws_size,
                              hipStream_t stream)
{
  const float* x  = (const float*)d_in[0];
  const float* P  = (const float*)d_in[1];
  const float* W0 = (const float*)d_in[2];
  const float* b0 = (const float*)d_in[3];
  const float* W1 = (const float*)d_in[4];
  const float* b1 = (const float*)d_in[5];
  const float* W2 = (const float*)d_in[6];
  const float* b2 = (const float*)d_in[7];
  float* out = (float*)d_out;
  int Npts = in_sizes[0] / XDIM;

  const size_t PT_BYTES = (size_t)3 * GSZ * GSZ * 32 * 2;  // ~50.5 MB
  const size_t WG_BYTES = (size_t)8192 * 8 * 2;            // 128 KB each
  char* ws = (char*)d_ws;
  int use_pt = (ws_size >= PT_BYTES + 2 * WG_BYTES) ? 1 : 0;
  unsigned short *Ptb, *W0g, *W1g;
  if (use_pt) {
    Ptb = (unsigned short*)ws;
    W0g = (unsigned short*)(ws + PT_BYTES);
    W1g = (unsigned short*)(ws + PT_BYTES + WG_BYTES);
  } else {
    Ptb = nullptr;
    W0g = (unsigned short*)ws;
    W1g = (unsigned short*)(ws + WG_BYTES);
  }

  prep_w<<<64, 256, 0, stream>>>(W0, W1, W0g, W1g);
  if (use_pt) prep_pt<<<(3 * GSZ * GSZ + 255) / 256, 256, 0, stream>>>(P, Ptb);

  int nblk = (Npts + 127) / 128;
  if (use_pt)
    sdf_main<1><<<nblk, 512, 0, stream>>>(x, P, Ptb, W0g, W1g, b0, b1, W2, b2, out, Npts);
  else
    sdf_main<0><<<nblk, 512, 0, stream>>>(x, P, Ptb, W0g, W1g, b0, b1, W2, b2, out, Npts);
}